// Round 16
// baseline (87.073 us; speedup 1.0000x reference)
//
#include <hip/hip_runtime.h>

// Predictor: MLP3 (Linear+BN(train)+ReLU x2, Linear) -> LSTM(64), 1 cond + 25 self-feed steps.
// B=16384, OUT=128 (x3 -> 384), HID=32, LSTM_H=64, NPRED=25. Output (B,25,64) fp32.
// All GEMMs via split-precision bf16 MFMA: P = A_hi*B_hi + A_hi*B_lo + A_lo*B_hi (fp32 accum).
// BN stats BIT-DETERMINISTIC (slot partials + fixed-order reduce; float atomics diverge replays).
// k_lstm (R16 = R15 with compiling pin): 512-thr blocks, 8 waves; wave = (group, u-quadrant);
// 4 waves/SIMD. R14's (512,2) squeezed VGPR to 64 and rematerialized weights from L2 in-loop.
// Fix: __launch_bounds__(512) only + per-dword asm-pinned weight fragments (R15's uint4 "+v"
// constraint doesn't compile -- "tied indirect register inputs"; scalar dwords do).
// History: R9/R10 wave-private regressed; R11 reorder+setprio regressed; R12 barrier-halving
// null; R13 s_sleep de-phasing null. Never cap VGPR below need (R4/R5: spill, 3x slowdown).

#define EPSV 1e-5f
#define LOG2E 1.4426950408889634f
#define K2    2.8853900817779268f   // 2*log2e

typedef __attribute__((ext_vector_type(8))) short bf16x8;
typedef __attribute__((ext_vector_type(4))) float f32x4;

__device__ __forceinline__ float rcp_f(float x) { return __builtin_amdgcn_rcpf(x); }
__device__ __forceinline__ void split_bf16(float x, ushort& hi, ushort& lo) {
    unsigned xb = __builtin_bit_cast(unsigned, x);
    hi = (ushort)(xb >> 16);
    float hif = __builtin_bit_cast(float, xb & 0xffff0000u);
    unsigned lb = __builtin_bit_cast(unsigned, x - hif);
    lo = (ushort)(lb >> 16);
}
__device__ __forceinline__ void split8(const float* w, bf16x8& hiv, bf16x8& lov) {
    ushort hs[8], ls[8];
    #pragma unroll
    for (int j = 0; j < 8; ++j) split_bf16(w[j], hs[j], ls[j]);
    hiv = *(bf16x8*)hs;
    lov = *(bf16x8*)ls;
}
// make a fragment opaque to the compiler (kills load rematerialization; value unchanged).
// NOTE: must pin dword-by-dword -- vector-typed "+v" operands fail to compile on gfx950.
__device__ __forceinline__ void pin_frag(bf16x8& f) {
    uint4 t = __builtin_bit_cast(uint4, f);
    asm volatile("" : "+v"(t.x), "+v"(t.y), "+v"(t.z), "+v"(t.w));
    f = __builtin_bit_cast(bf16x8, t);
}

// ---------------- k_red: per-channel fixed-order BN-stats reduce (+ optional LSTM weight prep) ----
__global__ __launch_bounds__(256) void k_red(
    const float* __restrict__ part, const float* __restrict__ g,
    const float* __restrict__ be, float* __restrict__ scsh,
    int do_prep,
    const float* __restrict__ Wih, const float* __restrict__ Whh,
    const float* __restrict__ bih, const float* __restrict__ bhh,
    ushort* __restrict__ Wih_hi, ushort* __restrict__ Wih_lo,
    ushort* __restrict__ Wsum_hi, ushort* __restrict__ Wsum_lo,
    float* __restrict__ bsum)
{
    __shared__ float rs[256], rq[256];
    const int ch = blockIdx.x, t = threadIdx.x;

    if (do_prep) {
        #pragma unroll
        for (int e = 0; e < 2; ++e) {
            int i = blockIdx.x * 512 + e * 256 + t;
            int j = i >> 6;
            float sc = (j >= 128 && j < 192) ? K2 : LOG2E;
            float wi  = Wih[i] * sc;
            float wsv = (Wih[i] + Whh[i]) * sc;
            ushort h, l;
            split_bf16(wi, h, l);  Wih_hi[i] = h;  Wih_lo[i] = l;
            split_bf16(wsv, h, l); Wsum_hi[i] = h; Wsum_lo[i] = l;
        }
        if (blockIdx.x == 0) {
            float sc = (t >= 128 && t < 192) ? K2 : LOG2E;
            bsum[t] = (bih[t] + bhh[t]) * sc;
        }
    }

    float s = (part[t * 32 + ch] + part[(t + 256) * 32 + ch]) +
              (part[(t + 512) * 32 + ch] + part[(t + 768) * 32 + ch]);
    float q = (part[32768 + t * 32 + ch] + part[32768 + (t + 256) * 32 + ch]) +
              (part[32768 + (t + 512) * 32 + ch] + part[32768 + (t + 768) * 32 + ch]);
    rs[t] = s; rq[t] = q;
    __syncthreads();
    #pragma unroll
    for (int off = 128; off > 0; off >>= 1) {
        if (t < off) { rs[t] += rs[t + off]; rq[t] += rq[t + off]; }
        __syncthreads();
    }
    if (t == 0) {
        float mu = rs[0] * (1.f / 16384.f);
        float va = rq[0] * (1.f / 16384.f) - mu * mu;
        float sc = g[ch] * rsqrtf(va + EPSV);
        scsh[ch] = sc; scsh[32 + ch] = be[ch] - mu * sc;
    }
}

// ---------------- kernel 1: pre = [x0|x1|x2] @ W1^T + b1 (MFMA), + BN1 partial stats ----------------
__global__ __launch_bounds__(256, 2) void k_mlp1(
    const float* __restrict__ x0, const float* __restrict__ x1, const float* __restrict__ x2,
    const float* __restrict__ W1, const float* __restrict__ b1,
    float* __restrict__ pre, float* __restrict__ st1p)
{
    __shared__ __align__(16) ushort xhi[32 * 392];
    __shared__ __align__(16) ushort xlo[32 * 392];
    const int tid = threadIdx.x;
    const int r0  = blockIdx.x * 32;
    const int lane = tid & 63, l15 = lane & 15, lg = lane >> 4, q = tid >> 6;
    const int m0 = (q & 1) * 16, n0 = (q >> 1) * 16;

    bf16x8 WH[12], WL[12];
    {
        const float* wsrc = W1 + (size_t)(n0 + l15) * 384 + lg * 8;
        #pragma unroll
        for (int kt = 0; kt < 12; ++kt) {
            float w[8];
            float4 wa = *(const float4*)(wsrc + kt * 32);
            float4 wb = *(const float4*)(wsrc + kt * 32 + 4);
            w[0] = wa.x; w[1] = wa.y; w[2] = wa.z; w[3] = wa.w;
            w[4] = wb.x; w[5] = wb.y; w[6] = wb.z; w[7] = wb.w;
            split8(w, WH[kt], WL[kt]);
        }
    }

    for (int a = 0; a < 3; ++a) {
        const float* xp = (a == 0) ? x0 : (a == 1) ? x1 : x2;
        const float4* src = (const float4*)(xp + (size_t)r0 * 128);
        #pragma unroll
        for (int it = 0; it < 4; ++it) {
            int i = it * 256 + tid;
            int row = i >> 5, c4 = i & 31;
            float4 v = src[i];
            ushort h0, l0, h1, l1, h2, l2, h3, l3;
            split_bf16(v.x, h0, l0); split_bf16(v.y, h1, l1);
            split_bf16(v.z, h2, l2); split_bf16(v.w, h3, l3);
            int ofs = row * 392 + a * 128 + c4 * 4;
            *(ushort4*)&xhi[ofs] = make_ushort4(h0, h1, h2, h3);
            *(ushort4*)&xlo[ofs] = make_ushort4(l0, l1, l2, l3);
        }
    }
    __syncthreads();

    const float bias = b1[n0 + l15];
    f32x4 acc = {bias, bias, bias, bias};
    #pragma unroll
    for (int kt = 0; kt < 12; ++kt) {
        bf16x8 ahi = *(const bf16x8*)&xhi[(m0 + l15) * 392 + kt * 32 + lg * 8];
        bf16x8 alo = *(const bf16x8*)&xlo[(m0 + l15) * 392 + kt * 32 + lg * 8];
        acc = __builtin_amdgcn_mfma_f32_16x16x32_bf16(ahi, WH[kt], acc, 0, 0, 0);
        acc = __builtin_amdgcn_mfma_f32_16x16x32_bf16(ahi, WL[kt], acc, 0, 0, 0);
        acc = __builtin_amdgcn_mfma_f32_16x16x32_bf16(alo, WH[kt], acc, 0, 0, 0);
    }
    #pragma unroll
    for (int rg = 0; rg < 4; ++rg)
        pre[(size_t)(r0 + m0 + lg * 4 + rg) * 32 + n0 + l15] = acc[rg];
    float s  = (acc[0] + acc[1]) + (acc[2] + acc[3]);
    float sq = (acc[0] * acc[0] + acc[1] * acc[1]) + (acc[2] * acc[2] + acc[3] * acc[3]);
    s  += __shfl_xor(s, 16);  s  += __shfl_xor(s, 32);
    sq += __shfl_xor(sq, 16); sq += __shfl_xor(sq, 32);
    if (lg == 0) {
        int slot = (blockIdx.x * 2 + (q & 1)) * 32 + n0 + l15;
        st1p[slot] = s;
        st1p[32768 + slot] = sq;
    }
}

// ---------------- kernel 2: h1 = relu(BN1(pre)); pre = h1 @ W2^T + b2 IN-PLACE; BN2 partials ----------------
__global__ __launch_bounds__(256) void k_mlp2(
    float* __restrict__ pre, const float* __restrict__ scsh1,
    const float* __restrict__ W2, const float* __restrict__ b2,
    float* __restrict__ st2p)
{
    __shared__ __align__(16) ushort hhi[32 * 40];
    __shared__ __align__(16) ushort hlo[32 * 40];
    const int tid = threadIdx.x;
    const int r0  = blockIdx.x * 32;
    const int lane = tid & 63, l15 = lane & 15, lg = lane >> 4, q = tid >> 6;
    const int m0 = (q & 1) * 16, n0 = (q >> 1) * 16;

    bf16x8 W2H, W2L;
    {
        const float* wsrc = W2 + (size_t)(n0 + l15) * 32 + lg * 8;
        float w[8];
        float4 wa = *(const float4*)(wsrc);
        float4 wb = *(const float4*)(wsrc + 4);
        w[0] = wa.x; w[1] = wa.y; w[2] = wa.z; w[3] = wa.w;
        w[4] = wb.x; w[5] = wb.y; w[6] = wb.z; w[7] = wb.w;
        split8(w, W2H, W2L);
    }

    {
        int row = tid >> 3, c4 = tid & 7;
        float4 scv = *(const float4*)(scsh1 + c4 * 4);
        float4 shv = *(const float4*)(scsh1 + 32 + c4 * 4);
        float4 v = ((const float4*)(pre + (size_t)r0 * 32))[tid];
        float e0 = fmaxf(fmaf(v.x, scv.x, shv.x), 0.f);
        float e1 = fmaxf(fmaf(v.y, scv.y, shv.y), 0.f);
        float e2 = fmaxf(fmaf(v.z, scv.z, shv.z), 0.f);
        float e3 = fmaxf(fmaf(v.w, scv.w, shv.w), 0.f);
        ushort h0, l0, h1, l1, h2, l2, h3, l3;
        split_bf16(e0, h0, l0); split_bf16(e1, h1, l1);
        split_bf16(e2, h2, l2); split_bf16(e3, h3, l3);
        int ofs = row * 40 + c4 * 4;
        *(ushort4*)&hhi[ofs] = make_ushort4(h0, h1, h2, h3);
        *(ushort4*)&hlo[ofs] = make_ushort4(l0, l1, l2, l3);
    }
    __syncthreads();

    const float bias = b2[n0 + l15];
    f32x4 acc = {bias, bias, bias, bias};
    bf16x8 ahi = *(const bf16x8*)&hhi[(m0 + l15) * 40 + lg * 8];
    bf16x8 alo = *(const bf16x8*)&hlo[(m0 + l15) * 40 + lg * 8];
    acc = __builtin_amdgcn_mfma_f32_16x16x32_bf16(ahi, W2H, acc, 0, 0, 0);
    acc = __builtin_amdgcn_mfma_f32_16x16x32_bf16(ahi, W2L, acc, 0, 0, 0);
    acc = __builtin_amdgcn_mfma_f32_16x16x32_bf16(alo, W2H, acc, 0, 0, 0);

    #pragma unroll
    for (int rg = 0; rg < 4; ++rg)
        pre[(size_t)(r0 + m0 + lg * 4 + rg) * 32 + n0 + l15] = acc[rg];
    float s  = (acc[0] + acc[1]) + (acc[2] + acc[3]);
    float sq = (acc[0] * acc[0] + acc[1] * acc[1]) + (acc[2] * acc[2] + acc[3] * acc[3]);
    s  += __shfl_xor(s, 16);  s  += __shfl_xor(s, 32);
    sq += __shfl_xor(sq, 16); sq += __shfl_xor(sq, 32);
    if (lg == 0) {
        int slot = (blockIdx.x * 2 + (q & 1)) * 32 + n0 + l15;
        st2p[slot] = s;
        st2p[32768 + slot] = sq;
    }
}

// ---------------- kernel 3: BN2 -> ReLU -> m -> 26-step LSTM, 8 waves x half-work ----------------
// 512 blocks x 512 thr; block = 32 rows = groups A(0..15), B(16..31). Wave w = (g=w&1, qd=w>>1).
// Per wave per step: 24 MFMA + 4-cell ACT; target 4 waves/SIMD with RESIDENT weights (~110 VGPR).
__global__ __launch_bounds__(512) void k_lstm(
    const float* __restrict__ pre, const float* __restrict__ scsh2,
    const float* __restrict__ W3, const float* __restrict__ b3,
    const ushort* __restrict__ Wih_hi, const ushort* __restrict__ Wih_lo,
    const ushort* __restrict__ Wsum_hi, const ushort* __restrict__ Wsum_lo,
    const float* __restrict__ bsum, float* __restrict__ out)
{
    __shared__ __align__(16) ushort hhi[2][2][16][72];  // [group][buf][row][u]
    __shared__ __align__(16) ushort hlo[2][2][16][72];
    __shared__ float bn2sc[32], bn2sh[32];
    const int tid  = threadIdx.x;
    const int lane = tid & 63, l15 = lane & 15, lg = lane >> 4;
    const int w = tid >> 6, g = w & 1, qd = w >> 1;
    const int r0   = blockIdx.x * 32;

    if (tid < 32) { bn2sc[tid] = scsh2[tid]; bn2sh[tid] = scsh2[32 + tid]; }
    __syncthreads();

    // ---- MLP tail: m = relu(BN2(pre)) @ W3^T + b3 for 32 rows; 512 thr -> 4 u each
    {
        const int row = tid & 31, seg = tid >> 5;
        float h2[32];
        const float4* pr = (const float4*)(pre + (size_t)(r0 + row) * 32);
        #pragma unroll
        for (int j4 = 0; j4 < 8; ++j4) {
            float4 v = pr[j4];
            h2[j4 * 4 + 0] = v.x; h2[j4 * 4 + 1] = v.y;
            h2[j4 * 4 + 2] = v.z; h2[j4 * 4 + 3] = v.w;
        }
        #pragma unroll
        for (int j = 0; j < 32; ++j) h2[j] = fmaxf(fmaf(h2[j], bn2sc[j], bn2sh[j]), 0.f);
        #pragma unroll
        for (int uu = 0; uu < 4; ++uu) {
            int u = seg * 4 + uu;
            const float* wp = W3 + u * 32;
            float a0 = 0.f, a1 = 0.f, a2 = 0.f, a3 = 0.f;
            #pragma unroll
            for (int k = 0; k < 32; k += 4) {
                a0 = fmaf(h2[k + 0], wp[k + 0], a0);
                a1 = fmaf(h2[k + 1], wp[k + 1], a1);
                a2 = fmaf(h2[k + 2], wp[k + 2], a2);
                a3 = fmaf(h2[k + 3], wp[k + 3], a3);
            }
            float m = b3[u] + ((a0 + a1) + (a2 + a3));
            ushort mh, ml; split_bf16(m, mh, ml);
            hhi[row >> 4][0][row & 15][u] = mh;
            hlo[row >> 4][0][row & 15][u] = ml;
        }
    }

    float bias[4];
    #pragma unroll
    for (int nt = 0; nt < 4; ++nt) bias[nt] = bsum[nt * 64 + qd * 16 + l15];
    float c[4] = {0.f, 0.f, 0.f, 0.f};

    float* ob[4];
    #pragma unroll
    for (int rg = 0; rg < 4; ++rg)
        ob[rg] = out + (size_t)(r0 + g * 16 + lg * 4 + rg) * 1600 + (qd * 16 + l15);

    bf16x8 Bhi[4][2], Blo[4][2];
    const size_t wofs = (size_t)(qd * 16 + l15) * 64 + lg * 8;
    #pragma unroll
    for (int nt = 0; nt < 4; ++nt)
        #pragma unroll
        for (int kt = 0; kt < 2; ++kt) {
            Bhi[nt][kt] = *(const bf16x8*)(Wih_hi + (size_t)nt * 4096 + wofs + kt * 32);
            Blo[nt][kt] = *(const bf16x8*)(Wih_lo + (size_t)nt * 4096 + wofs + kt * 32);
            pin_frag(Bhi[nt][kt]);   // keep resident: compiler cannot rematerialize
            pin_frag(Blo[nt][kt]);
        }
    __syncthreads();

#define MFMA_GATES(ACC, BUF)                                                     \
    {                                                                            \
        _Pragma("unroll")                                                        \
        for (int nt = 0; nt < 4; ++nt)                                           \
            ACC[nt] = (f32x4){bias[nt], bias[nt], bias[nt], bias[nt]};           \
        _Pragma("unroll")                                                        \
        for (int kt = 0; kt < 2; ++kt) {                                         \
            bf16x8 ahi = *(const bf16x8*)&hhi[g][BUF][l15][kt * 32 + lg * 8];    \
            bf16x8 alo = *(const bf16x8*)&hlo[g][BUF][l15][kt * 32 + lg * 8];    \
            _Pragma("unroll")                                                    \
            for (int nt = 0; nt < 4; ++nt) {                                     \
                ACC[nt] = __builtin_amdgcn_mfma_f32_16x16x32_bf16(ahi, Bhi[nt][kt], ACC[nt], 0, 0, 0); \
                ACC[nt] = __builtin_amdgcn_mfma_f32_16x16x32_bf16(ahi, Blo[nt][kt], ACC[nt], 0, 0, 0); \
                ACC[nt] = __builtin_amdgcn_mfma_f32_16x16x32_bf16(alo, Bhi[nt][kt], ACC[nt], 0, 0, 0); \
            }                                                                    \
        }                                                                        \
    }

    // exp2-domain activations: i,f,o scaled by log2e; g by 2log2e (baked into W/bsum).
#define ACT(ACC, WBUF, SLOT, WRST)                                               \
    {                                                                            \
        const int u = qd * 16 + l15;                                             \
        _Pragma("unroll")                                                        \
        for (int rg = 0; rg < 4; ++rg) {                                         \
            int row = lg * 4 + rg;                                               \
            float iv = ACC[0][rg], fv = ACC[1][rg];                              \
            float gv = ACC[2][rg], ov = ACC[3][rg];                              \
            float Af = __builtin_amdgcn_exp2f(-fv);                              \
            float Ai = __builtin_amdgcn_exp2f(-iv);                              \
            float Bg = __builtin_amdgcn_exp2f(gv);                               \
            float sig = (Bg - 1.f) * rcp_f((1.f + Ai) * (Bg + 1.f));             \
            float cc = c[rg] * rcp_f(1.f + Af) + sig;                            \
            c[rg] = cc;                                                          \
            float Ao = __builtin_amdgcn_exp2f(-ov);                              \
            float C2 = __builtin_amdgcn_exp2f(cc * K2);                          \
            float hn = (C2 - 1.f) * rcp_f((1.f + Ao) * (C2 + 1.f));              \
            ushort hh, hl; split_bf16(hn, hh, hl);                               \
            hhi[g][WBUF][row][u] = hh;                                           \
            hlo[g][WBUF][row][u] = hl;                                           \
            if (WRST)                                                            \
                ob[rg][(size_t)(SLOT) * 64] = hn;                                \
        }                                                                        \
    }

    f32x4 acc[4];

    // ---- prologue: step 0 (input m in buf 0, weights Wih); h^1 -> buf 1, no output
    MFMA_GATES(acc, 0);
    #pragma unroll
    for (int nt = 0; nt < 4; ++nt)
        #pragma unroll
        for (int kt = 0; kt < 2; ++kt) {
            Bhi[nt][kt] = *(const bf16x8*)(Wsum_hi + (size_t)nt * 4096 + wofs + kt * 32);
            Blo[nt][kt] = *(const bf16x8*)(Wsum_lo + (size_t)nt * 4096 + wofs + kt * 32);
            pin_frag(Bhi[nt][kt]);
            pin_frag(Blo[nt][kt]);
        }
    ACT(acc, 1, 0, 0);
    __syncthreads();

    // ---- steady: 1 barrier per step; h^s in buf[s&1]; h^{s+1} -> out slot s-1
    #pragma unroll 1
    for (int s = 1; s <= 25; ++s) {
        const int rb = s & 1, wb = rb ^ 1;
        MFMA_GATES(acc, rb);
        ACT(acc, wb, s - 1, 1);
        __syncthreads();
    }

#undef MFMA_GATES
#undef ACT
}

extern "C" void kernel_launch(void* const* d_in, const int* in_sizes, int n_in,
                              void* d_out, int out_size, void* d_ws, size_t ws_size,
                              hipStream_t stream) {
    const float* x0   = (const float*)d_in[0];
    const float* x1   = (const float*)d_in[1];
    const float* x2   = (const float*)d_in[2];
    const float* W1   = (const float*)d_in[3];
    const float* b1   = (const float*)d_in[4];
    const float* g1   = (const float*)d_in[5];
    const float* be1  = (const float*)d_in[6];
    const float* W2   = (const float*)d_in[7];
    const float* b2   = (const float*)d_in[8];
    const float* g2   = (const float*)d_in[9];
    const float* be2  = (const float*)d_in[10];
    const float* W3   = (const float*)d_in[11];
    const float* b3   = (const float*)d_in[12];
    const float* Wih  = (const float*)d_in[13];
    const float* Whh  = (const float*)d_in[14];
    const float* bih  = (const float*)d_in[15];
    const float* bhh  = (const float*)d_in[16];

    float* ws    = (float*)d_ws;
    float* pre   = ws;                   // 524288 floats (pre1, then pre2 in-place)
    float* st1p  = ws + 524288;          // 65536
    float* st2p  = ws + 589824;          // 65536
    float* scsh1 = ws + 655360;          // 64
    float* scsh2 = ws + 655424;          // 64
    float* bsum  = ws + 655488;          // 256
    ushort* ub   = (ushort*)(ws + 655744);
    ushort* Wih_hi  = ub;                // 16384
    ushort* Wih_lo  = ub + 16384;
    ushort* Wsum_hi = ub + 32768;
    ushort* Wsum_lo = ub + 49152;        // end 65536 ushorts

    hipLaunchKernelGGL(k_mlp1, dim3(512), dim3(256), 0, stream,
                       x0, x1, x2, W1, b1, pre, st1p);
    hipLaunchKernelGGL(k_red, dim3(32), dim3(256), 0, stream,
                       st1p, g1, be1, scsh1,
                       1, Wih, Whh, bih, bhh, Wih_hi, Wih_lo, Wsum_hi, Wsum_lo, bsum);
    hipLaunchKernelGGL(k_mlp2, dim3(512), dim3(256), 0, stream,
                       pre, scsh1, W2, b2, st2p);
    hipLaunchKernelGGL(k_red, dim3(32), dim3(256), 0, stream,
                       st2p, g2, be2, scsh2,
                       0, Wih, Whh, bih, bhh, Wih_hi, Wih_lo, Wsum_hi, Wsum_lo, bsum);
    hipLaunchKernelGGL(k_lstm, dim3(512), dim3(512), 0, stream,
                       pre, scsh2, W3, b3,
                       Wih_hi, Wih_lo, Wsum_hi, Wsum_lo, bsum, (float*)d_out);
}

// Round 17
// 84.822 us; speedup vs baseline: 1.0265x; 1.0265x over previous
//
#include <hip/hip_runtime.h>

// Predictor: MLP3 (Linear+BN(train)+ReLU x2, Linear) -> LSTM(64), 1 cond + 25 self-feed steps.
// B=16384, OUT=128 (x3 -> 384), HID=32, LSTM_H=64, NPRED=25. Output (B,25,64) fp32.
// All GEMMs via split-precision bf16 MFMA: P = A_hi*B_hi + A_hi*B_lo + A_lo*B_hi (fp32 accum).
// BN stats BIT-DETERMINISTIC (slot partials + fixed-order reduce; float atomics diverge replays).
// k_lstm (R17 = R12 + MFMA dep-latency fix): dual-group, 1 barrier/step, 2 blocks/CU.
// MFMA_GATES uses kt-split DUAL accumulators -> 8 independent 3-deep chains (was 4x 6-deep,
// latency-exposed: MFMA busy-cycles were ~3x the throughput cost). ACT: one-rcp cc fusion.
// History: R9/R10 wave-private (1 wave/SIMD) regressed; R11 reorder+setprio regressed; R12
// barrier-halving null; R13 s_sleep null; R14-R16 4-waves/SIMD unrunnable (allocator pins
// VGPR=64 and rematerializes weights). Never cap VGPR below need (R4/R5: spill, 3x slowdown).

#define EPSV 1e-5f
#define LOG2E 1.4426950408889634f
#define K2    2.8853900817779268f   // 2*log2e

typedef __attribute__((ext_vector_type(8))) short bf16x8;
typedef __attribute__((ext_vector_type(4))) float f32x4;

__device__ __forceinline__ float rcp_f(float x) { return __builtin_amdgcn_rcpf(x); }
__device__ __forceinline__ void split_bf16(float x, ushort& hi, ushort& lo) {
    unsigned xb = __builtin_bit_cast(unsigned, x);
    hi = (ushort)(xb >> 16);
    float hif = __builtin_bit_cast(float, xb & 0xffff0000u);
    unsigned lb = __builtin_bit_cast(unsigned, x - hif);
    lo = (ushort)(lb >> 16);
}
__device__ __forceinline__ void split8(const float* w, bf16x8& hiv, bf16x8& lov) {
    ushort hs[8], ls[8];
    #pragma unroll
    for (int j = 0; j < 8; ++j) split_bf16(w[j], hs[j], ls[j]);
    hiv = *(bf16x8*)hs;
    lov = *(bf16x8*)ls;
}

// ---------------- k_red: per-channel fixed-order BN-stats reduce (+ optional LSTM weight prep) ----
__global__ __launch_bounds__(256) void k_red(
    const float* __restrict__ part, const float* __restrict__ g,
    const float* __restrict__ be, float* __restrict__ scsh,
    int do_prep,
    const float* __restrict__ Wih, const float* __restrict__ Whh,
    const float* __restrict__ bih, const float* __restrict__ bhh,
    ushort* __restrict__ Wih_hi, ushort* __restrict__ Wih_lo,
    ushort* __restrict__ Wsum_hi, ushort* __restrict__ Wsum_lo,
    float* __restrict__ bsum)
{
    __shared__ float rs[256], rq[256];
    const int ch = blockIdx.x, t = threadIdx.x;

    if (do_prep) {
        #pragma unroll
        for (int e = 0; e < 2; ++e) {
            int i = blockIdx.x * 512 + e * 256 + t;
            int j = i >> 6;
            float sc = (j >= 128 && j < 192) ? K2 : LOG2E;
            float wi  = Wih[i] * sc;
            float wsv = (Wih[i] + Whh[i]) * sc;
            ushort h, l;
            split_bf16(wi, h, l);  Wih_hi[i] = h;  Wih_lo[i] = l;
            split_bf16(wsv, h, l); Wsum_hi[i] = h; Wsum_lo[i] = l;
        }
        if (blockIdx.x == 0) {
            float sc = (t >= 128 && t < 192) ? K2 : LOG2E;
            bsum[t] = (bih[t] + bhh[t]) * sc;
        }
    }

    float s = (part[t * 32 + ch] + part[(t + 256) * 32 + ch]) +
              (part[(t + 512) * 32 + ch] + part[(t + 768) * 32 + ch]);
    float q = (part[32768 + t * 32 + ch] + part[32768 + (t + 256) * 32 + ch]) +
              (part[32768 + (t + 512) * 32 + ch] + part[32768 + (t + 768) * 32 + ch]);
    rs[t] = s; rq[t] = q;
    __syncthreads();
    #pragma unroll
    for (int off = 128; off > 0; off >>= 1) {
        if (t < off) { rs[t] += rs[t + off]; rq[t] += rq[t + off]; }
        __syncthreads();
    }
    if (t == 0) {
        float mu = rs[0] * (1.f / 16384.f);
        float va = rq[0] * (1.f / 16384.f) - mu * mu;
        float sc = g[ch] * rsqrtf(va + EPSV);
        scsh[ch] = sc; scsh[32 + ch] = be[ch] - mu * sc;
    }
}

// ---------------- kernel 1: pre = [x0|x1|x2] @ W1^T + b1 (MFMA), + BN1 partial stats ----------------
// 512 blocks x 256 thr; W1 register fragments; 2-way kt-split accumulators (dep-latency).
__global__ __launch_bounds__(256, 2) void k_mlp1(
    const float* __restrict__ x0, const float* __restrict__ x1, const float* __restrict__ x2,
    const float* __restrict__ W1, const float* __restrict__ b1,
    float* __restrict__ pre, float* __restrict__ st1p)
{
    __shared__ __align__(16) ushort xhi[32 * 392];
    __shared__ __align__(16) ushort xlo[32 * 392];
    const int tid = threadIdx.x;
    const int r0  = blockIdx.x * 32;
    const int lane = tid & 63, l15 = lane & 15, lg = lane >> 4, q = tid >> 6;
    const int m0 = (q & 1) * 16, n0 = (q >> 1) * 16;

    bf16x8 WH[12], WL[12];
    {
        const float* wsrc = W1 + (size_t)(n0 + l15) * 384 + lg * 8;
        #pragma unroll
        for (int kt = 0; kt < 12; ++kt) {
            float w[8];
            float4 wa = *(const float4*)(wsrc + kt * 32);
            float4 wb = *(const float4*)(wsrc + kt * 32 + 4);
            w[0] = wa.x; w[1] = wa.y; w[2] = wa.z; w[3] = wa.w;
            w[4] = wb.x; w[5] = wb.y; w[6] = wb.z; w[7] = wb.w;
            split8(w, WH[kt], WL[kt]);
        }
    }

    for (int a = 0; a < 3; ++a) {
        const float* xp = (a == 0) ? x0 : (a == 1) ? x1 : x2;
        const float4* src = (const float4*)(xp + (size_t)r0 * 128);
        #pragma unroll
        for (int it = 0; it < 4; ++it) {
            int i = it * 256 + tid;
            int row = i >> 5, c4 = i & 31;
            float4 v = src[i];
            ushort h0, l0, h1, l1, h2, l2, h3, l3;
            split_bf16(v.x, h0, l0); split_bf16(v.y, h1, l1);
            split_bf16(v.z, h2, l2); split_bf16(v.w, h3, l3);
            int ofs = row * 392 + a * 128 + c4 * 4;
            *(ushort4*)&xhi[ofs] = make_ushort4(h0, h1, h2, h3);
            *(ushort4*)&xlo[ofs] = make_ushort4(l0, l1, l2, l3);
        }
    }
    __syncthreads();

    const float bias = b1[n0 + l15];
    f32x4 acc  = {bias, bias, bias, bias};
    f32x4 acc2 = {0.f, 0.f, 0.f, 0.f};
    #pragma unroll
    for (int kt = 0; kt < 12; ++kt) {
        bf16x8 ahi = *(const bf16x8*)&xhi[(m0 + l15) * 392 + kt * 32 + lg * 8];
        bf16x8 alo = *(const bf16x8*)&xlo[(m0 + l15) * 392 + kt * 32 + lg * 8];
        if (kt & 1) {
            acc2 = __builtin_amdgcn_mfma_f32_16x16x32_bf16(ahi, WH[kt], acc2, 0, 0, 0);
            acc2 = __builtin_amdgcn_mfma_f32_16x16x32_bf16(ahi, WL[kt], acc2, 0, 0, 0);
            acc2 = __builtin_amdgcn_mfma_f32_16x16x32_bf16(alo, WH[kt], acc2, 0, 0, 0);
        } else {
            acc = __builtin_amdgcn_mfma_f32_16x16x32_bf16(ahi, WH[kt], acc, 0, 0, 0);
            acc = __builtin_amdgcn_mfma_f32_16x16x32_bf16(ahi, WL[kt], acc, 0, 0, 0);
            acc = __builtin_amdgcn_mfma_f32_16x16x32_bf16(alo, WH[kt], acc, 0, 0, 0);
        }
    }
    acc = acc + acc2;
    #pragma unroll
    for (int rg = 0; rg < 4; ++rg)
        pre[(size_t)(r0 + m0 + lg * 4 + rg) * 32 + n0 + l15] = acc[rg];
    float s  = (acc[0] + acc[1]) + (acc[2] + acc[3]);
    float sq = (acc[0] * acc[0] + acc[1] * acc[1]) + (acc[2] * acc[2] + acc[3] * acc[3]);
    s  += __shfl_xor(s, 16);  s  += __shfl_xor(s, 32);
    sq += __shfl_xor(sq, 16); sq += __shfl_xor(sq, 32);
    if (lg == 0) {
        int slot = (blockIdx.x * 2 + (q & 1)) * 32 + n0 + l15;
        st1p[slot] = s;
        st1p[32768 + slot] = sq;
    }
}

// ---------------- kernel 2: h1 = relu(BN1(pre)); pre = h1 @ W2^T + b2 IN-PLACE; BN2 partials ----------------
__global__ __launch_bounds__(256) void k_mlp2(
    float* __restrict__ pre, const float* __restrict__ scsh1,
    const float* __restrict__ W2, const float* __restrict__ b2,
    float* __restrict__ st2p)
{
    __shared__ __align__(16) ushort hhi[32 * 40];
    __shared__ __align__(16) ushort hlo[32 * 40];
    const int tid = threadIdx.x;
    const int r0  = blockIdx.x * 32;
    const int lane = tid & 63, l15 = lane & 15, lg = lane >> 4, q = tid >> 6;
    const int m0 = (q & 1) * 16, n0 = (q >> 1) * 16;

    bf16x8 W2H, W2L;
    {
        const float* wsrc = W2 + (size_t)(n0 + l15) * 32 + lg * 8;
        float w[8];
        float4 wa = *(const float4*)(wsrc);
        float4 wb = *(const float4*)(wsrc + 4);
        w[0] = wa.x; w[1] = wa.y; w[2] = wa.z; w[3] = wa.w;
        w[4] = wb.x; w[5] = wb.y; w[6] = wb.z; w[7] = wb.w;
        split8(w, W2H, W2L);
    }

    {
        int row = tid >> 3, c4 = tid & 7;
        float4 scv = *(const float4*)(scsh1 + c4 * 4);
        float4 shv = *(const float4*)(scsh1 + 32 + c4 * 4);
        float4 v = ((const float4*)(pre + (size_t)r0 * 32))[tid];
        float e0 = fmaxf(fmaf(v.x, scv.x, shv.x), 0.f);
        float e1 = fmaxf(fmaf(v.y, scv.y, shv.y), 0.f);
        float e2 = fmaxf(fmaf(v.z, scv.z, shv.z), 0.f);
        float e3 = fmaxf(fmaf(v.w, scv.w, shv.w), 0.f);
        ushort h0, l0, h1, l1, h2, l2, h3, l3;
        split_bf16(e0, h0, l0); split_bf16(e1, h1, l1);
        split_bf16(e2, h2, l2); split_bf16(e3, h3, l3);
        int ofs = row * 40 + c4 * 4;
        *(ushort4*)&hhi[ofs] = make_ushort4(h0, h1, h2, h3);
        *(ushort4*)&hlo[ofs] = make_ushort4(l0, l1, l2, l3);
    }
    __syncthreads();

    const float bias = b2[n0 + l15];
    f32x4 acc = {bias, bias, bias, bias};
    bf16x8 ahi = *(const bf16x8*)&hhi[(m0 + l15) * 40 + lg * 8];
    bf16x8 alo = *(const bf16x8*)&hlo[(m0 + l15) * 40 + lg * 8];
    acc = __builtin_amdgcn_mfma_f32_16x16x32_bf16(ahi, W2H, acc, 0, 0, 0);
    acc = __builtin_amdgcn_mfma_f32_16x16x32_bf16(ahi, W2L, acc, 0, 0, 0);
    acc = __builtin_amdgcn_mfma_f32_16x16x32_bf16(alo, W2H, acc, 0, 0, 0);

    #pragma unroll
    for (int rg = 0; rg < 4; ++rg)
        pre[(size_t)(r0 + m0 + lg * 4 + rg) * 32 + n0 + l15] = acc[rg];
    float s  = (acc[0] + acc[1]) + (acc[2] + acc[3]);
    float sq = (acc[0] * acc[0] + acc[1] * acc[1]) + (acc[2] * acc[2] + acc[3] * acc[3]);
    s  += __shfl_xor(s, 16);  s  += __shfl_xor(s, 32);
    sq += __shfl_xor(sq, 16); sq += __shfl_xor(sq, 32);
    if (lg == 0) {
        int slot = (blockIdx.x * 2 + (q & 1)) * 32 + n0 + l15;
        st2p[slot] = s;
        st2p[32768 + slot] = sq;
    }
}

// ---------------- kernel 3: BN2 -> ReLU -> m -> 26-step LSTM, 1 barrier/step ----------------
// 512 blocks x 256 thr; block = 32 rows = groups A(0..15), B(16..31); wave q owns u-quadrant.
// Step = { MFMA A; MFMA B; ACT A; ACT B; barrier }. kt-split dual accumulators per group.
__global__ __launch_bounds__(256, 2) void k_lstm(
    const float* __restrict__ pre, const float* __restrict__ scsh2,
    const float* __restrict__ W3, const float* __restrict__ b3,
    const ushort* __restrict__ Wih_hi, const ushort* __restrict__ Wih_lo,
    const ushort* __restrict__ Wsum_hi, const ushort* __restrict__ Wsum_lo,
    const float* __restrict__ bsum, float* __restrict__ out)
{
    __shared__ __align__(16) ushort hhi[2][2][16][72];  // [group][buf][row][u]
    __shared__ __align__(16) ushort hlo[2][2][16][72];
    __shared__ float bn2sc[32], bn2sh[32];
    const int tid  = threadIdx.x;
    const int lane = tid & 63, l15 = lane & 15, lg = lane >> 4, q = tid >> 6;
    const int r0   = blockIdx.x * 32;

    if (tid < 32) { bn2sc[tid] = scsh2[tid]; bn2sh[tid] = scsh2[32 + tid]; }
    __syncthreads();

    // ---- MLP tail: m = relu(BN2(pre)) @ W3^T + b3 for 32 rows; write into buf 0 of each group
    {
        const int row = tid & 31, seg = tid >> 5;
        float h2[32];
        const float4* pr = (const float4*)(pre + (size_t)(r0 + row) * 32);
        #pragma unroll
        for (int j4 = 0; j4 < 8; ++j4) {
            float4 v = pr[j4];
            h2[j4 * 4 + 0] = v.x; h2[j4 * 4 + 1] = v.y;
            h2[j4 * 4 + 2] = v.z; h2[j4 * 4 + 3] = v.w;
        }
        #pragma unroll
        for (int j = 0; j < 32; ++j) h2[j] = fmaxf(fmaf(h2[j], bn2sc[j], bn2sh[j]), 0.f);
        #pragma unroll
        for (int uu = 0; uu < 8; ++uu) {
            int u = seg * 8 + uu;
            const float* w = W3 + u * 32;
            float a0 = 0.f, a1 = 0.f, a2 = 0.f, a3 = 0.f;
            #pragma unroll
            for (int k = 0; k < 32; k += 4) {
                a0 = fmaf(h2[k + 0], w[k + 0], a0);
                a1 = fmaf(h2[k + 1], w[k + 1], a1);
                a2 = fmaf(h2[k + 2], w[k + 2], a2);
                a3 = fmaf(h2[k + 3], w[k + 3], a3);
            }
            float m = b3[u] + ((a0 + a1) + (a2 + a3));
            ushort mh, ml; split_bf16(m, mh, ml);
            hhi[row >> 4][0][row & 15][u] = mh;
            hlo[row >> 4][0][row & 15][u] = ml;
        }
    }

    float bias[4];
    #pragma unroll
    for (int nt = 0; nt < 4; ++nt) bias[nt] = bsum[nt * 64 + q * 16 + l15];
    float cA[4] = {0.f, 0.f, 0.f, 0.f}, cB[4] = {0.f, 0.f, 0.f, 0.f};

    float* obA[4];
    float* obB[4];
    #pragma unroll
    for (int rg = 0; rg < 4; ++rg) {
        obA[rg] = out + (size_t)(r0 + lg * 4 + rg) * 1600 + (q * 16 + l15);
        obB[rg] = out + (size_t)(r0 + 16 + lg * 4 + rg) * 1600 + (q * 16 + l15);
    }

    bf16x8 Bhi[4][2], Blo[4][2];
    const size_t wofs = (size_t)(q * 16 + l15) * 64 + lg * 8;
    #pragma unroll
    for (int nt = 0; nt < 4; ++nt)
        #pragma unroll
        for (int kt = 0; kt < 2; ++kt) {
            Bhi[nt][kt] = *(const bf16x8*)(Wih_hi + (size_t)nt * 4096 + wofs + kt * 32);
            Blo[nt][kt] = *(const bf16x8*)(Wih_lo + (size_t)nt * 4096 + wofs + kt * 32);
        }
    __syncthreads();

    // kt-split dual accumulators: 8 independent 3-deep MFMA chains (latency-covered)
#define MFMA_GATES(ACC, G, BUF)                                                  \
    {                                                                            \
        f32x4 _a2[4];                                                            \
        _Pragma("unroll")                                                        \
        for (int nt = 0; nt < 4; ++nt) {                                         \
            ACC[nt] = (f32x4){bias[nt], bias[nt], bias[nt], bias[nt]};           \
            _a2[nt] = (f32x4){0.f, 0.f, 0.f, 0.f};                               \
        }                                                                        \
        bf16x8 ahi0 = *(const bf16x8*)&hhi[G][BUF][l15][lg * 8];                 \
        bf16x8 alo0 = *(const bf16x8*)&hlo[G][BUF][l15][lg * 8];                 \
        bf16x8 ahi1 = *(const bf16x8*)&hhi[G][BUF][l15][32 + lg * 8];            \
        bf16x8 alo1 = *(const bf16x8*)&hlo[G][BUF][l15][32 + lg * 8];            \
        _Pragma("unroll")                                                        \
        for (int nt = 0; nt < 4; ++nt) {                                         \
            ACC[nt] = __builtin_amdgcn_mfma_f32_16x16x32_bf16(ahi0, Bhi[nt][0], ACC[nt], 0, 0, 0); \
            ACC[nt] = __builtin_amdgcn_mfma_f32_16x16x32_bf16(ahi0, Blo[nt][0], ACC[nt], 0, 0, 0); \
            ACC[nt] = __builtin_amdgcn_mfma_f32_16x16x32_bf16(alo0, Bhi[nt][0], ACC[nt], 0, 0, 0); \
            _a2[nt] = __builtin_amdgcn_mfma_f32_16x16x32_bf16(ahi1, Bhi[nt][1], _a2[nt], 0, 0, 0); \
            _a2[nt] = __builtin_amdgcn_mfma_f32_16x16x32_bf16(ahi1, Blo[nt][1], _a2[nt], 0, 0, 0); \
            _a2[nt] = __builtin_amdgcn_mfma_f32_16x16x32_bf16(alo1, Bhi[nt][1], _a2[nt], 0, 0, 0); \
        }                                                                        \
        _Pragma("unroll")                                                        \
        for (int nt = 0; nt < 4; ++nt) ACC[nt] = ACC[nt] + _a2[nt];              \
    }

    // exp2-domain activations; one-rcp fused cell update:
    // cc = (c*t + (Bg-1)(1+Af)) / (t*(1+Af)), t=(1+Ai)(Bg+1)  [== c*sigm(f)+sigm(i)tanh(g)]
#define ACT(ACC, C, G, WBUF, OB, SLOT, WRST)                                     \
    {                                                                            \
        const int u = q * 16 + l15;                                              \
        _Pragma("unroll")                                                        \
        for (int rg = 0; rg < 4; ++rg) {                                         \
            int row = lg * 4 + rg;                                               \
            float iv = ACC[0][rg], fv = ACC[1][rg];                              \
            float gv = ACC[2][rg], ov = ACC[3][rg];                              \
            float Af = __builtin_amdgcn_exp2f(-fv);                              \
            float Ai = __builtin_amdgcn_exp2f(-iv);                              \
            float Bg = __builtin_amdgcn_exp2f(gv);                               \
            float onA = 1.f + Af;                                                \
            float t   = (1.f + Ai) * (Bg + 1.f);                                 \
            float cc  = fmaf(C[rg], t, (Bg - 1.f) * onA) * rcp_f(t * onA);       \
            C[rg] = cc;                                                          \
            float Ao = __builtin_amdgcn_exp2f(-ov);                              \
            float C2 = __builtin_amdgcn_exp2f(cc * K2);                          \
            float hn = (C2 - 1.f) * rcp_f((1.f + Ao) * (C2 + 1.f));              \
            ushort hh, hl; split_bf16(hn, hh, hl);                               \
            hhi[G][WBUF][row][u] = hh;                                           \
            hlo[G][WBUF][row][u] = hl;                                           \
            if (WRST)                                                            \
                OB[rg][(size_t)(SLOT) * 64] = hn;                                \
        }                                                                        \
    }

    f32x4 accA[4], accB[4];

    // ---- prologue: step 0 (input m in buf 0, weights Wih); h^1 -> buf 1, no output
    MFMA_GATES(accA, 0, 0);
    MFMA_GATES(accB, 1, 0);
    #pragma unroll
    for (int nt = 0; nt < 4; ++nt)
        #pragma unroll
        for (int kt = 0; kt < 2; ++kt) {
            Bhi[nt][kt] = *(const bf16x8*)(Wsum_hi + (size_t)nt * 4096 + wofs + kt * 32);
            Blo[nt][kt] = *(const bf16x8*)(Wsum_lo + (size_t)nt * 4096 + wofs + kt * 32);
        }
    ACT(accA, cA, 0, 1, obA, 0, 0);
    ACT(accB, cB, 1, 1, obB, 0, 0);
    __syncthreads();

    // ---- steady: 1 barrier per step; h^s in buf[s&1]; h^{s+1} -> out slot s-1
    #pragma unroll 1
    for (int s = 1; s <= 25; ++s) {
        const int rb = s & 1, wb = rb ^ 1;
        MFMA_GATES(accA, 0, rb);
        MFMA_GATES(accB, 1, rb);
        ACT(accA, cA, 0, wb, obA, s - 1, 1);
        ACT(accB, cB, 1, wb, obB, s - 1, 1);
        __syncthreads();
    }

#undef MFMA_GATES
#undef ACT
}

extern "C" void kernel_launch(void* const* d_in, const int* in_sizes, int n_in,
                              void* d_out, int out_size, void* d_ws, size_t ws_size,
                              hipStream_t stream) {
    const float* x0   = (const float*)d_in[0];
    const float* x1   = (const float*)d_in[1];
    const float* x2   = (const float*)d_in[2];
    const float* W1   = (const float*)d_in[3];
    const float* b1   = (const float*)d_in[4];
    const float* g1   = (const float*)d_in[5];
    const float* be1  = (const float*)d_in[6];
    const float* W2   = (const float*)d_in[7];
    const float* b2   = (const float*)d_in[8];
    const float* g2   = (const float*)d_in[9];
    const float* be2  = (const float*)d_in[10];
    const float* W3   = (const float*)d_in[11];
    const float* b3   = (const float*)d_in[12];
    const float* Wih  = (const float*)d_in[13];
    const float* Whh  = (const float*)d_in[14];
    const float* bih  = (const float*)d_in[15];
    const float* bhh  = (const float*)d_in[16];

    float* ws    = (float*)d_ws;
    float* pre   = ws;                   // 524288 floats (pre1, then pre2 in-place)
    float* st1p  = ws + 524288;          // 65536
    float* st2p  = ws + 589824;          // 65536
    float* scsh1 = ws + 655360;          // 64
    float* scsh2 = ws + 655424;          // 64
    float* bsum  = ws + 655488;          // 256
    ushort* ub   = (ushort*)(ws + 655744);
    ushort* Wih_hi  = ub;                // 16384
    ushort* Wih_lo  = ub + 16384;
    ushort* Wsum_hi = ub + 32768;
    ushort* Wsum_lo = ub + 49152;        // end 65536 ushorts

    hipLaunchKernelGGL(k_mlp1, dim3(512), dim3(256), 0, stream,
                       x0, x1, x2, W1, b1, pre, st1p);
    hipLaunchKernelGGL(k_red, dim3(32), dim3(256), 0, stream,
                       st1p, g1, be1, scsh1,
                       1, Wih, Whh, bih, bhh, Wih_hi, Wih_lo, Wsum_hi, Wsum_lo, bsum);
    hipLaunchKernelGGL(k_mlp2, dim3(512), dim3(256), 0, stream,
                       pre, scsh1, W2, b2, st2p);
    hipLaunchKernelGGL(k_red, dim3(32), dim3(256), 0, stream,
                       st2p, g2, be2, scsh2,
                       0, Wih, Whh, bih, bhh, Wih_hi, Wih_lo, Wsum_hi, Wsum_lo, bsum);
    hipLaunchKernelGGL(k_lstm, dim3(512), dim3(256), 0, stream,
                       pre, scsh2, W3, b3,
                       Wih_hi, Wih_lo, Wsum_hi, Wsum_lo, bsum, (float*)d_out);
}

// Round 18
// 82.002 us; speedup vs baseline: 1.0618x; 1.0344x over previous
//
#include <hip/hip_runtime.h>

// Predictor: MLP3 (Linear+BN(train)+ReLU x2, Linear) -> LSTM(64), 1 cond + 25 self-feed steps.
// B=16384, OUT=128 (x3 -> 384), HID=32, LSTM_H=64, NPRED=25. Output (B,25,64) fp32.
// All GEMMs via split-precision bf16 MFMA: P = A_hi*B_hi + A_hi*B_lo + A_lo*B_hi (fp32 accum).
// BN stats BIT-DETERMINISTIC (slot partials + fixed-order reduce; float atomics diverge replays).
// FINAL (R18 = R13, best measured 82.1us): k_lstm dual-group ping-pong, 1 barrier/step,
// 2 blocks/CU, exp2-domain activations (weights pre-scaled by log2e / 2log2e).
// Structural floor: LSTM step = ~900cyc MFMA + ~900cyc dependent VALU/trans chain per wave with
// mandatory exchange between them; tested 1/2/4 waves/SIMD, 1-2 barriers/step, reordering,
// setprio, sleep-stagger, in-register exchange, acc ILP splits -- all land 64-87us for k_lstm.
// NOTE: never cap VGPR below need via __launch_bounds__ min-waves (R4/R5: spill, 3x slowdown).

#define EPSV 1e-5f
#define LOG2E 1.4426950408889634f
#define K2    2.8853900817779268f   // 2*log2e

typedef __attribute__((ext_vector_type(8))) short bf16x8;
typedef __attribute__((ext_vector_type(4))) float f32x4;

__device__ __forceinline__ float rcp_f(float x) { return __builtin_amdgcn_rcpf(x); }
__device__ __forceinline__ void split_bf16(float x, ushort& hi, ushort& lo) {
    unsigned xb = __builtin_bit_cast(unsigned, x);
    hi = (ushort)(xb >> 16);
    float hif = __builtin_bit_cast(float, xb & 0xffff0000u);
    unsigned lb = __builtin_bit_cast(unsigned, x - hif);
    lo = (ushort)(lb >> 16);
}
__device__ __forceinline__ void split8(const float* w, bf16x8& hiv, bf16x8& lov) {
    ushort hs[8], ls[8];
    #pragma unroll
    for (int j = 0; j < 8; ++j) split_bf16(w[j], hs[j], ls[j]);
    hiv = *(bf16x8*)hs;
    lov = *(bf16x8*)ls;
}

// ---------------- k_red: per-channel fixed-order BN-stats reduce (+ optional LSTM weight prep) ----
__global__ __launch_bounds__(256) void k_red(
    const float* __restrict__ part, const float* __restrict__ g,
    const float* __restrict__ be, float* __restrict__ scsh,
    int do_prep,
    const float* __restrict__ Wih, const float* __restrict__ Whh,
    const float* __restrict__ bih, const float* __restrict__ bhh,
    ushort* __restrict__ Wih_hi, ushort* __restrict__ Wih_lo,
    ushort* __restrict__ Wsum_hi, ushort* __restrict__ Wsum_lo,
    float* __restrict__ bsum)
{
    __shared__ float rs[256], rq[256];
    const int ch = blockIdx.x, t = threadIdx.x;

    if (do_prep) {
        #pragma unroll
        for (int e = 0; e < 2; ++e) {
            int i = blockIdx.x * 512 + e * 256 + t;
            int j = i >> 6;
            float sc = (j >= 128 && j < 192) ? K2 : LOG2E;
            float wi  = Wih[i] * sc;
            float wsv = (Wih[i] + Whh[i]) * sc;
            ushort h, l;
            split_bf16(wi, h, l);  Wih_hi[i] = h;  Wih_lo[i] = l;
            split_bf16(wsv, h, l); Wsum_hi[i] = h; Wsum_lo[i] = l;
        }
        if (blockIdx.x == 0) {
            float sc = (t >= 128 && t < 192) ? K2 : LOG2E;
            bsum[t] = (bih[t] + bhh[t]) * sc;
        }
    }

    float s = (part[t * 32 + ch] + part[(t + 256) * 32 + ch]) +
              (part[(t + 512) * 32 + ch] + part[(t + 768) * 32 + ch]);
    float q = (part[32768 + t * 32 + ch] + part[32768 + (t + 256) * 32 + ch]) +
              (part[32768 + (t + 512) * 32 + ch] + part[32768 + (t + 768) * 32 + ch]);
    rs[t] = s; rq[t] = q;
    __syncthreads();
    #pragma unroll
    for (int off = 128; off > 0; off >>= 1) {
        if (t < off) { rs[t] += rs[t + off]; rq[t] += rq[t + off]; }
        __syncthreads();
    }
    if (t == 0) {
        float mu = rs[0] * (1.f / 16384.f);
        float va = rq[0] * (1.f / 16384.f) - mu * mu;
        float sc = g[ch] * rsqrtf(va + EPSV);
        scsh[ch] = sc; scsh[32 + ch] = be[ch] - mu * sc;
    }
}

// ---------------- kernel 1: pre = [x0|x1|x2] @ W1^T + b1 (MFMA), + BN1 partial stats ----------------
// 512 blocks x 256 thr; W1 self-split into register fragments.
__global__ __launch_bounds__(256, 2) void k_mlp1(
    const float* __restrict__ x0, const float* __restrict__ x1, const float* __restrict__ x2,
    const float* __restrict__ W1, const float* __restrict__ b1,
    float* __restrict__ pre, float* __restrict__ st1p)
{
    __shared__ __align__(16) ushort xhi[32 * 392];
    __shared__ __align__(16) ushort xlo[32 * 392];
    const int tid = threadIdx.x;
    const int r0  = blockIdx.x * 32;
    const int lane = tid & 63, l15 = lane & 15, lg = lane >> 4, q = tid >> 6;
    const int m0 = (q & 1) * 16, n0 = (q >> 1) * 16;

    bf16x8 WH[12], WL[12];
    {
        const float* wsrc = W1 + (size_t)(n0 + l15) * 384 + lg * 8;
        #pragma unroll
        for (int kt = 0; kt < 12; ++kt) {
            float w[8];
            float4 wa = *(const float4*)(wsrc + kt * 32);
            float4 wb = *(const float4*)(wsrc + kt * 32 + 4);
            w[0] = wa.x; w[1] = wa.y; w[2] = wa.z; w[3] = wa.w;
            w[4] = wb.x; w[5] = wb.y; w[6] = wb.z; w[7] = wb.w;
            split8(w, WH[kt], WL[kt]);
        }
    }

    for (int a = 0; a < 3; ++a) {
        const float* xp = (a == 0) ? x0 : (a == 1) ? x1 : x2;
        const float4* src = (const float4*)(xp + (size_t)r0 * 128);
        #pragma unroll
        for (int it = 0; it < 4; ++it) {
            int i = it * 256 + tid;
            int row = i >> 5, c4 = i & 31;
            float4 v = src[i];
            ushort h0, l0, h1, l1, h2, l2, h3, l3;
            split_bf16(v.x, h0, l0); split_bf16(v.y, h1, l1);
            split_bf16(v.z, h2, l2); split_bf16(v.w, h3, l3);
            int ofs = row * 392 + a * 128 + c4 * 4;
            *(ushort4*)&xhi[ofs] = make_ushort4(h0, h1, h2, h3);
            *(ushort4*)&xlo[ofs] = make_ushort4(l0, l1, l2, l3);
        }
    }
    __syncthreads();

    const float bias = b1[n0 + l15];
    f32x4 acc = {bias, bias, bias, bias};
    #pragma unroll
    for (int kt = 0; kt < 12; ++kt) {
        bf16x8 ahi = *(const bf16x8*)&xhi[(m0 + l15) * 392 + kt * 32 + lg * 8];
        bf16x8 alo = *(const bf16x8*)&xlo[(m0 + l15) * 392 + kt * 32 + lg * 8];
        acc = __builtin_amdgcn_mfma_f32_16x16x32_bf16(ahi, WH[kt], acc, 0, 0, 0);
        acc = __builtin_amdgcn_mfma_f32_16x16x32_bf16(ahi, WL[kt], acc, 0, 0, 0);
        acc = __builtin_amdgcn_mfma_f32_16x16x32_bf16(alo, WH[kt], acc, 0, 0, 0);
    }
    #pragma unroll
    for (int rg = 0; rg < 4; ++rg)
        pre[(size_t)(r0 + m0 + lg * 4 + rg) * 32 + n0 + l15] = acc[rg];
    float s  = (acc[0] + acc[1]) + (acc[2] + acc[3]);
    float sq = (acc[0] * acc[0] + acc[1] * acc[1]) + (acc[2] * acc[2] + acc[3] * acc[3]);
    s  += __shfl_xor(s, 16);  s  += __shfl_xor(s, 32);
    sq += __shfl_xor(sq, 16); sq += __shfl_xor(sq, 32);
    if (lg == 0) {
        int slot = (blockIdx.x * 2 + (q & 1)) * 32 + n0 + l15;
        st1p[slot] = s;
        st1p[32768 + slot] = sq;
    }
}

// ---------------- kernel 2: h1 = relu(BN1(pre)); pre = h1 @ W2^T + b2 IN-PLACE; BN2 partials ----------------
__global__ __launch_bounds__(256) void k_mlp2(
    float* __restrict__ pre, const float* __restrict__ scsh1,
    const float* __restrict__ W2, const float* __restrict__ b2,
    float* __restrict__ st2p)
{
    __shared__ __align__(16) ushort hhi[32 * 40];
    __shared__ __align__(16) ushort hlo[32 * 40];
    __shared__ float bnsc[32], bnsh[32];
    const int tid = threadIdx.x;
    const int r0  = blockIdx.x * 32;
    const int lane = tid & 63, l15 = lane & 15, lg = lane >> 4, q = tid >> 6;
    const int m0 = (q & 1) * 16, n0 = (q >> 1) * 16;

    bf16x8 W2H, W2L;
    {
        const float* wsrc = W2 + (size_t)(n0 + l15) * 32 + lg * 8;
        float w[8];
        float4 wa = *(const float4*)(wsrc);
        float4 wb = *(const float4*)(wsrc + 4);
        w[0] = wa.x; w[1] = wa.y; w[2] = wa.z; w[3] = wa.w;
        w[4] = wb.x; w[5] = wb.y; w[6] = wb.z; w[7] = wb.w;
        split8(w, W2H, W2L);
    }

    if (tid < 32) { bnsc[tid] = scsh1[tid]; bnsh[tid] = scsh1[32 + tid]; }
    __syncthreads();
    {
        int row = tid >> 3, c4 = tid & 7;
        float4 v = ((const float4*)(pre + (size_t)r0 * 32))[tid];
        float e0 = fmaxf(fmaf(v.x, bnsc[c4 * 4 + 0], bnsh[c4 * 4 + 0]), 0.f);
        float e1 = fmaxf(fmaf(v.y, bnsc[c4 * 4 + 1], bnsh[c4 * 4 + 1]), 0.f);
        float e2 = fmaxf(fmaf(v.z, bnsc[c4 * 4 + 2], bnsh[c4 * 4 + 2]), 0.f);
        float e3 = fmaxf(fmaf(v.w, bnsc[c4 * 4 + 3], bnsh[c4 * 4 + 3]), 0.f);
        ushort h0, l0, h1, l1, h2, l2, h3, l3;
        split_bf16(e0, h0, l0); split_bf16(e1, h1, l1);
        split_bf16(e2, h2, l2); split_bf16(e3, h3, l3);
        int ofs = row * 40 + c4 * 4;
        *(ushort4*)&hhi[ofs] = make_ushort4(h0, h1, h2, h3);
        *(ushort4*)&hlo[ofs] = make_ushort4(l0, l1, l2, l3);
    }
    __syncthreads();

    const float bias = b2[n0 + l15];
    f32x4 acc = {bias, bias, bias, bias};
    bf16x8 ahi = *(const bf16x8*)&hhi[(m0 + l15) * 40 + lg * 8];
    bf16x8 alo = *(const bf16x8*)&hlo[(m0 + l15) * 40 + lg * 8];
    acc = __builtin_amdgcn_mfma_f32_16x16x32_bf16(ahi, W2H, acc, 0, 0, 0);
    acc = __builtin_amdgcn_mfma_f32_16x16x32_bf16(ahi, W2L, acc, 0, 0, 0);
    acc = __builtin_amdgcn_mfma_f32_16x16x32_bf16(alo, W2H, acc, 0, 0, 0);

    #pragma unroll
    for (int rg = 0; rg < 4; ++rg)
        pre[(size_t)(r0 + m0 + lg * 4 + rg) * 32 + n0 + l15] = acc[rg];
    float s  = (acc[0] + acc[1]) + (acc[2] + acc[3]);
    float sq = (acc[0] * acc[0] + acc[1] * acc[1]) + (acc[2] * acc[2] + acc[3] * acc[3]);
    s  += __shfl_xor(s, 16);  s  += __shfl_xor(s, 32);
    sq += __shfl_xor(sq, 16); sq += __shfl_xor(sq, 32);
    if (lg == 0) {
        int slot = (blockIdx.x * 2 + (q & 1)) * 32 + n0 + l15;
        st2p[slot] = s;
        st2p[32768 + slot] = sq;
    }
}

// ---------------- kernel 3: BN2 -> ReLU -> m -> 26-step LSTM, 1 barrier/step ----------------
// 512 blocks x 256 thr; block = 32 rows = groups A(0..15), B(16..31); wave q owns u-quadrant.
// Step = { MFMA A; MFMA B; ACT A; ACT B; barrier }.
__global__ __launch_bounds__(256, 2) void k_lstm(
    const float* __restrict__ pre, const float* __restrict__ scsh2,
    const float* __restrict__ W3, const float* __restrict__ b3,
    const ushort* __restrict__ Wih_hi, const ushort* __restrict__ Wih_lo,
    const ushort* __restrict__ Wsum_hi, const ushort* __restrict__ Wsum_lo,
    const float* __restrict__ bsum, float* __restrict__ out)
{
    __shared__ __align__(16) ushort hhi[2][2][16][72];  // [group][buf][row][u]
    __shared__ __align__(16) ushort hlo[2][2][16][72];
    __shared__ float bn2sc[32], bn2sh[32];
    const int tid  = threadIdx.x;
    const int lane = tid & 63, l15 = lane & 15, lg = lane >> 4, q = tid >> 6;
    const int r0   = blockIdx.x * 32;

    if (tid < 32) { bn2sc[tid] = scsh2[tid]; bn2sh[tid] = scsh2[32 + tid]; }
    __syncthreads();

    // ---- MLP tail: m = relu(BN2(pre)) @ W3^T + b3 for 32 rows; write into buf 0 of each group
    {
        const int row = tid & 31, seg = tid >> 5;
        float h2[32];
        const float4* pr = (const float4*)(pre + (size_t)(r0 + row) * 32);
        #pragma unroll
        for (int j4 = 0; j4 < 8; ++j4) {
            float4 v = pr[j4];
            h2[j4 * 4 + 0] = v.x; h2[j4 * 4 + 1] = v.y;
            h2[j4 * 4 + 2] = v.z; h2[j4 * 4 + 3] = v.w;
        }
        #pragma unroll
        for (int j = 0; j < 32; ++j) h2[j] = fmaxf(fmaf(h2[j], bn2sc[j], bn2sh[j]), 0.f);
        #pragma unroll
        for (int uu = 0; uu < 8; ++uu) {
            int u = seg * 8 + uu;
            const float* w = W3 + u * 32;
            float a0 = 0.f, a1 = 0.f, a2 = 0.f, a3 = 0.f;
            #pragma unroll
            for (int k = 0; k < 32; k += 4) {
                a0 = fmaf(h2[k + 0], w[k + 0], a0);
                a1 = fmaf(h2[k + 1], w[k + 1], a1);
                a2 = fmaf(h2[k + 2], w[k + 2], a2);
                a3 = fmaf(h2[k + 3], w[k + 3], a3);
            }
            float m = b3[u] + ((a0 + a1) + (a2 + a3));
            ushort mh, ml; split_bf16(m, mh, ml);
            hhi[row >> 4][0][row & 15][u] = mh;
            hlo[row >> 4][0][row & 15][u] = ml;
        }
    }

    float bias[4];
    #pragma unroll
    for (int nt = 0; nt < 4; ++nt) bias[nt] = bsum[nt * 64 + q * 16 + l15];
    float cA[4] = {0.f, 0.f, 0.f, 0.f}, cB[4] = {0.f, 0.f, 0.f, 0.f};

    float* obA[4];
    float* obB[4];
    #pragma unroll
    for (int rg = 0; rg < 4; ++rg) {
        obA[rg] = out + (size_t)(r0 + lg * 4 + rg) * 1600 + (q * 16 + l15);
        obB[rg] = out + (size_t)(r0 + 16 + lg * 4 + rg) * 1600 + (q * 16 + l15);
    }

    bf16x8 Bhi[4][2], Blo[4][2];
    const size_t wofs = (size_t)(q * 16 + l15) * 64 + lg * 8;
    #pragma unroll
    for (int nt = 0; nt < 4; ++nt)
        #pragma unroll
        for (int kt = 0; kt < 2; ++kt) {
            Bhi[nt][kt] = *(const bf16x8*)(Wih_hi + (size_t)nt * 4096 + wofs + kt * 32);
            Blo[nt][kt] = *(const bf16x8*)(Wih_lo + (size_t)nt * 4096 + wofs + kt * 32);
        }
    __syncthreads();

#define MFMA_GATES(ACC, G, BUF)                                                  \
    {                                                                            \
        _Pragma("unroll")                                                        \
        for (int nt = 0; nt < 4; ++nt)                                           \
            ACC[nt] = (f32x4){bias[nt], bias[nt], bias[nt], bias[nt]};           \
        _Pragma("unroll")                                                        \
        for (int kt = 0; kt < 2; ++kt) {                                         \
            bf16x8 ahi = *(const bf16x8*)&hhi[G][BUF][l15][kt * 32 + lg * 8];    \
            bf16x8 alo = *(const bf16x8*)&hlo[G][BUF][l15][kt * 32 + lg * 8];    \
            _Pragma("unroll")                                                    \
            for (int nt = 0; nt < 4; ++nt) {                                     \
                ACC[nt] = __builtin_amdgcn_mfma_f32_16x16x32_bf16(ahi, Bhi[nt][kt], ACC[nt], 0, 0, 0); \
                ACC[nt] = __builtin_amdgcn_mfma_f32_16x16x32_bf16(ahi, Blo[nt][kt], ACC[nt], 0, 0, 0); \
                ACC[nt] = __builtin_amdgcn_mfma_f32_16x16x32_bf16(alo, Bhi[nt][kt], ACC[nt], 0, 0, 0); \
            }                                                                    \
        }                                                                        \
    }

    // exp2-domain activations: i,f,o scaled by log2e; g by 2log2e (baked into W/bsum).
#define ACT(ACC, C, G, WBUF, OB, SLOT, WRST)                                     \
    {                                                                            \
        const int u = q * 16 + l15;                                              \
        _Pragma("unroll")                                                        \
        for (int rg = 0; rg < 4; ++rg) {                                         \
            int row = lg * 4 + rg;                                               \
            float iv = ACC[0][rg], fv = ACC[1][rg];                              \
            float gv = ACC[2][rg], ov = ACC[3][rg];                              \
            float Af = __builtin_amdgcn_exp2f(-fv);                              \
            float Ai = __builtin_amdgcn_exp2f(-iv);                              \
            float Bg = __builtin_amdgcn_exp2f(gv);                               \
            float sig = (Bg - 1.f) * rcp_f((1.f + Ai) * (Bg + 1.f));             \
            float cc = C[rg] * rcp_f(1.f + Af) + sig;                            \
            C[rg] = cc;                                                          \
            float Ao = __builtin_amdgcn_exp2f(-ov);                              \
            float C2 = __builtin_amdgcn_exp2f(cc * K2);                          \
            float hn = (C2 - 1.f) * rcp_f((1.f + Ao) * (C2 + 1.f));              \
            ushort hh, hl; split_bf16(hn, hh, hl);                               \
            hhi[G][WBUF][row][u] = hh;                                           \
            hlo[G][WBUF][row][u] = hl;                                           \
            if (WRST)                                                            \
                OB[rg][(size_t)(SLOT) * 64] = hn;                                \
        }                                                                        \
    }

    f32x4 accA[4], accB[4];

    // ---- prologue: step 0 (input m in buf 0, weights Wih); h^1 -> buf 1, no output
    MFMA_GATES(accA, 0, 0);
    MFMA_GATES(accB, 1, 0);
    #pragma unroll
    for (int nt = 0; nt < 4; ++nt)
        #pragma unroll
        for (int kt = 0; kt < 2; ++kt) {
            Bhi[nt][kt] = *(const bf16x8*)(Wsum_hi + (size_t)nt * 4096 + wofs + kt * 32);
            Blo[nt][kt] = *(const bf16x8*)(Wsum_lo + (size_t)nt * 4096 + wofs + kt * 32);
        }
    ACT(accA, cA, 0, 1, obA, 0, 0);
    ACT(accB, cB, 1, 1, obB, 0, 0);
    __syncthreads();

    // ---- steady: 1 barrier per step; h^s in buf[s&1]; h^{s+1} -> out slot s-1
    #pragma unroll 1
    for (int s = 1; s <= 25; ++s) {
        const int rb = s & 1, wb = rb ^ 1;
        MFMA_GATES(accA, 0, rb);
        MFMA_GATES(accB, 1, rb);
        ACT(accA, cA, 0, wb, obA, s - 1, 1);
        ACT(accB, cB, 1, wb, obB, s - 1, 1);
        __syncthreads();
    }

#undef MFMA_GATES
#undef ACT
}

extern "C" void kernel_launch(void* const* d_in, const int* in_sizes, int n_in,
                              void* d_out, int out_size, void* d_ws, size_t ws_size,
                              hipStream_t stream) {
    const float* x0   = (const float*)d_in[0];
    const float* x1   = (const float*)d_in[1];
    const float* x2   = (const float*)d_in[2];
    const float* W1   = (const float*)d_in[3];
    const float* b1   = (const float*)d_in[4];
    const float* g1   = (const float*)d_in[5];
    const float* be1  = (const float*)d_in[6];
    const float* W2   = (const float*)d_in[7];
    const float* b2   = (const float*)d_in[8];
    const float* g2   = (const float*)d_in[9];
    const float* be2  = (const float*)d_in[10];
    const float* W3   = (const float*)d_in[11];
    const float* b3   = (const float*)d_in[12];
    const float* Wih  = (const float*)d_in[13];
    const float* Whh  = (const float*)d_in[14];
    const float* bih  = (const float*)d_in[15];
    const float* bhh  = (const float*)d_in[16];

    float* ws    = (float*)d_ws;
    float* pre   = ws;                   // 524288 floats (pre1, then pre2 in-place)
    float* st1p  = ws + 524288;          // 65536
    float* st2p  = ws + 589824;          // 65536
    float* scsh1 = ws + 655360;          // 64
    float* scsh2 = ws + 655424;          // 64
    float* bsum  = ws + 655488;          // 256
    ushort* ub   = (ushort*)(ws + 655744);
    ushort* Wih_hi  = ub;                // 16384
    ushort* Wih_lo  = ub + 16384;
    ushort* Wsum_hi = ub + 32768;
    ushort* Wsum_lo = ub + 49152;        // end 65536 ushorts

    hipLaunchKernelGGL(k_mlp1, dim3(512), dim3(256), 0, stream,
                       x0, x1, x2, W1, b1, pre, st1p);
    hipLaunchKernelGGL(k_red, dim3(32), dim3(256), 0, stream,
                       st1p, g1, be1, scsh1,
                       1, Wih, Whh, bih, bhh, Wih_hi, Wih_lo, Wsum_hi, Wsum_lo, bsum);
    hipLaunchKernelGGL(k_mlp2, dim3(512), dim3(256), 0, stream,
                       pre, scsh1, W2, b2, st2p);
    hipLaunchKernelGGL(k_red, dim3(32), dim3(256), 0, stream,
                       st2p, g2, be2, scsh2,
                       0, Wih, Whh, bih, bhh, Wih_hi, Wih_lo, Wsum_hi, Wsum_lo, bsum);
    hipLaunchKernelGGL(k_lstm, dim3(512), dim3(256), 0, stream,
                       pre, scsh2, W3, b3,
                       Wih_hi, Wih_lo, Wsum_hi, Wsum_lo, bsum, (float*)d_out);
}